// Round 1
// baseline (145.002 us; speedup 1.0000x reference)
//
#include <hip/hip_runtime.h>

#define BDIM 256
#define TILE 64
#define HALO 7
#define IN_T 78          // TILE + 2*HALO
#define LSTR 79          // LDS row stride (odd -> conflict-free-ish)
#define IMG_H 512
#define IMG_W 512
#define NPIX (16.0f * 512.0f * 512.0f)

__device__ __forceinline__ int reflect_idx(int i, int n) {
    // np.pad 'reflect' (no edge repeat): -k -> k ; (n-1)+k -> (n-1)-k
    i = (i < 0) ? -i : i;
    i = (i >= n) ? (2 * n - 2 - i) : i;
    return i;
}

// Computes the 16 dark-channel outputs owned by this thread for one image tile.
// cmin: [IN_T][LSTR] channel-min with halo; vm: [TILE][LSTR] vertical-min.
__device__ __forceinline__ void dark_tile(const float* __restrict__ X,
                                          float* __restrict__ cmin,
                                          float* __restrict__ vm,
                                          int tid, int r0g, int c0g,
                                          float (&o)[16]) {
    // Phase 1: reflect-pad load + channel min (raw values; affine deferred)
    for (int p = tid; p < IN_T * IN_T; p += BDIM) {
        int r = (unsigned)p / IN_T;
        int c = p - r * IN_T;
        int gr = reflect_idx(r0g + r, IMG_H);
        int gc = reflect_idx(c0g + c, IMG_W);
        const float* px = X + (size_t)gr * IMG_W + gc;
        float v = fminf(px[0], fminf(px[IMG_H * IMG_W], px[2 * IMG_H * IMG_W]));
        cmin[r * LSTR + c] = v;
    }
    __syncthreads();

    // Phase 2: vertical 15-window min, cmin[78][78] -> vm[64][78]
    // 312 tasks: (col 0..77) x (4 chunks of 16 output rows), Gil-Werman scan
    for (int t = tid; t < IN_T * 4; t += BDIM) {
        int col = (unsigned)t % IN_T;
        int rr0 = ((unsigned)t / IN_T) * 16;
        float s[15];
        #pragma unroll
        for (int j = 0; j < 15; ++j) s[j] = cmin[(rr0 + j) * LSTR + col];
        #pragma unroll
        for (int j = 13; j >= 0; --j) s[j] = fminf(s[j], s[j + 1]);
        vm[rr0 * LSTR + col] = s[0];
        float f = cmin[(rr0 + 15) * LSTR + col];
        #pragma unroll
        for (int i = 1; i <= 14; ++i) {
            vm[(rr0 + i) * LSTR + col] = fminf(s[i], f);
            f = fminf(f, cmin[(rr0 + 15 + i) * LSTR + col]);
        }
        vm[(rr0 + 15) * LSTR + col] = f;
    }
    __syncthreads();

    // Phase 3: horizontal 15-window min, vm[64][78] -> 16 regs/thread
    {
        int row = tid >> 2;
        int c0 = (tid & 3) * 16;
        const float* vr = vm + row * LSTR + c0;
        float s[15];
        #pragma unroll
        for (int j = 0; j < 15; ++j) s[j] = vr[j];
        #pragma unroll
        for (int j = 13; j >= 0; --j) s[j] = fminf(s[j], s[j + 1]);
        o[0] = s[0];
        float f = vr[15];
        #pragma unroll
        for (int i = 1; i <= 14; ++i) {
            o[i] = fminf(s[i], f);
            f = fminf(f, vr[15 + i]);
        }
        o[15] = f;
    }
    // NOTE: no trailing sync needed: next call's phase-1 touches only cmin,
    // and its own __syncthreads separates our vm reads from the next vm writes.
}

__global__ __launch_bounds__(BDIM)
void dcl_kernel(const float* __restrict__ real, const float* __restrict__ fake,
                float* __restrict__ out) {
    __shared__ float cmin[IN_T * LSTR];   // 24.6 KB
    __shared__ float vm[TILE * LSTR];     // 20.2 KB
    __shared__ float red[BDIM / 64];

    const int tid = threadIdx.x;
    const int r0g = blockIdx.y * TILE - HALO;
    const int c0g = blockIdx.x * TILE - HALO;
    const size_t ib = (size_t)blockIdx.z * 3 * IMG_H * IMG_W;

    float o_r[16], o_f[16];
    dark_tile(real + ib, cmin, vm, tid, r0g, c0g, o_r);
    dark_tile(fake + ib, cmin, vm, tid, r0g, c0g, o_f);

    // map -> clip((v+1)/2, 0, 0.1); MSE partial
    float acc = 0.f;
    #pragma unroll
    for (int i = 0; i < 16; ++i) {
        float a = fminf(fmaxf(0.5f * o_r[i] + 0.5f, 0.f), 0.1f);
        float b = fminf(fmaxf(0.5f * o_f[i] + 0.5f, 0.f), 0.1f);
        float d = a - b;
        acc += d * d;
    }
    // wave64 butterfly reduce
    #pragma unroll
    for (int off = 32; off >= 1; off >>= 1)
        acc += __shfl_xor(acc, off, 64);
    if ((tid & 63) == 0) red[tid >> 6] = acc;
    __syncthreads();
    if (tid == 0) {
        float t = red[0] + red[1] + red[2] + red[3];
        atomicAdd(out, t * (1.0f / NPIX));
    }
}

extern "C" void kernel_launch(void* const* d_in, const int* in_sizes, int n_in,
                              void* d_out, int out_size, void* d_ws, size_t ws_size,
                              hipStream_t stream) {
    const float* real = (const float*)d_in[0];
    const float* fake = (const float*)d_in[1];
    float* out = (float*)d_out;
    // harness poisons d_out with 0xAA before every launch; we accumulate via atomics
    hipMemsetAsync(out, 0, sizeof(float), stream);
    dim3 grid(IMG_W / TILE, IMG_H / TILE, 16);
    dcl_kernel<<<grid, BDIM, 0, stream>>>(real, fake, out);
}